// Round 11
// baseline (109.600 us; speedup 1.0000x reference)
//
#include <hip/hip_runtime.h>
#include <stdint.h>

// CausalMemory: out = ((q @ k^T) .* decay_mask) @ v @ Wo * scale
// B=4, T=2048, V=1024, D=512.  bf16 MFMA 16x16x32, fp32 accum.
// Round 11: N-loop multi-tile blocks (NSUB): A-frags read once per K-step,
// reused across NSUB B-subtiles -> 3x MFMA per fixed per-step overhead.
// QKV: NSUB=3, grid 256 = 1 block/CU.  out: NSUB=2, grid 256.
// (r10's fused f32 conversion reverted: +26us.  r9 merged prep kept.)

using bf16u = unsigned short;
using short8 = __attribute__((ext_vector_type(8))) short;
using f32x4  = __attribute__((ext_vector_type(4))) float;

__device__ __forceinline__ unsigned short f2bf(float f) {
  unsigned int u = __float_as_uint(f);
  u += 0x7fffu + ((u >> 16) & 1u);   // round-to-nearest-even
  return (unsigned short)(u >> 16);
}

__device__ __forceinline__ void gload16(const void* g, void* l) {
  __builtin_amdgcn_global_load_lds(
      (const __attribute__((address_space(1))) void*)g,
      (__attribute__((address_space(3))) void*)l, 16, 0, 0);
}

#define BK 32
#define TBM 128
#define TBN 128

// C = A @ Bt^T with row strides.  A: [M][ldA] bf16, Bt: [N][ldB] bf16.
// Block output: TBM x (NSUB * TBN), subtile s at col bn + s*(nbx*TBN).
// MODE 0: bf16 store.
// MODE 1: banded S: nbx=2 (delta); B rows start at (bm>>7 + delta)*128;
//         decay mask (0 for diff<=0 or col>=2048); store ldC=256 band.
// MODE 2: f32 * scale store (final out).
// MODE 3: R-band: A = S_band rows, B k-coords offset by bm&~127.
template<int MODE, int NSUB>
__global__ __launch_bounds__(256)
void gemm_bt(const bf16u* __restrict__ A, const bf16u* __restrict__ Bt,
             void* __restrict__ Cout,
             int K, int ldA, int ldB, int ldC,
             long sA, long sB, long sC,
             int nbx, const float* __restrict__ scal)
{
  constexpr int MF = 4, NF = 4;        // per-wave 64x64 per subtile
  constexpr int RA = 2, RB = 2;        // 4KB staging rounds per 128x32 tile

  __shared__ bf16u Al[2][TBM * BK];            // 2 x 8 KB
  __shared__ bf16u Bl[2][NSUB][TBN * BK];      // 2 x NSUB x 8 KB
  const int z = blockIdx.z;
  A  += (long)z * sA;
  Bt += (long)z * sB;

  // bijective XCD swizzle (m204) + row-major decode
  const int nwg  = gridDim.x;
  const int orig = blockIdx.x;
  const int q8 = nwg >> 3, r8 = nwg & 7;
  const int xcd = orig & 7, lid = orig >> 3;
  const int wgid = (xcd < r8 ? xcd * (q8 + 1)
                             : r8 * (q8 + 1) + (xcd - r8) * q8) + lid;
  const int by = wgid / nbx, bx = wgid - by * nbx;
  const int bm = by * TBM;
  const int bn = (MODE == 1) ? ((bm >> 7) + bx) * TBN : bx * TBN;
  const int sstride = nbx * TBN;               // col stride between subtiles
  const int kofsB = (MODE == 3) ? (bm & ~127) : 0;

  const int tid  = threadIdx.x;
  const int wid  = tid >> 6;
  const int lane = tid & 63;
  const int wr = (wid >> 1) * 64;
  const int wc = (wid & 1) * 64;

  f32x4 acc[NSUB][MF][NF] = {};

  // Staging: linear LDS dest (wave-uniform base + lane*16), pre-swizzled
  // global source.  LDS (row, chunk c) holds global chunk c ^ ((row>>1)&3).
  const int base0 = wid * 1024;
  const int lin0  = base0 + lane * 16;
  const int r0row = lin0 >> 6;            // 0..63 within a 4096-B round
  const int c16   = (lin0 >> 4) & 3;
  const int rcol  = (c16 ^ ((r0row >> 1) & 3)) << 3;

  const int nt = K / BK;

  auto stage = [&](int buf, int kk) {
#pragma unroll
    for (int r = 0; r < RA; ++r)
      gload16(A + (long)(bm + r * 64 + r0row) * ldA + kk + rcol,
              (char*)&Al[buf][0] + r * 4096 + base0);
#pragma unroll
    for (int s = 0; s < NSUB; ++s)
#pragma unroll
      for (int r = 0; r < RB; ++r)
        gload16(Bt + (long)(bn + s * sstride + r * 64 + r0row) * ldB + kofsB + kk + rcol,
                (char*)&Bl[buf][s][0] + r * 4096 + base0);
  };

  stage(0, 0);
  __syncthreads();

  const int fr = lane & 15;
  const int kc = lane >> 4;
  int cur = 0;
  for (int t = 0; t < nt; ++t) {
    if (t + 1 < nt) stage(cur ^ 1, (t + 1) * BK);
    short8 af[MF];
#pragma unroll
    for (int m = 0; m < MF; ++m) {
      int row = wr + m * 16 + fr;
      af[m] = *(const short8*)&Al[cur][row * BK + ((kc ^ ((row >> 1) & 3)) << 3)];
    }
#pragma unroll
    for (int s = 0; s < NSUB; ++s) {
      short8 bfr[NF];
#pragma unroll
      for (int n = 0; n < NF; ++n) {
        int row = wc + n * 16 + fr;
        bfr[n] = *(const short8*)&Bl[cur][s][row * BK + ((kc ^ ((row >> 1) & 3)) << 3)];
      }
#pragma unroll
      for (int m = 0; m < MF; ++m)
#pragma unroll
        for (int n = 0; n < NF; ++n)
          acc[s][m][n] = __builtin_amdgcn_mfma_f32_16x16x32_bf16(
              af[m], bfr[n], acc[s][m][n], 0, 0, 0);
    }
    __syncthreads();
    cur ^= 1;
  }

  // Epilogue.  C/D layout: col = lane&15, row = (lane>>4)*4 + j  (m89/m91)
  const int cc = lane & 15;
  const int cr = (lane >> 4) * 4;
  float mul = 1.0f, l2d = 0.0f;
  if (MODE == 1) {
    float dlv = scal[0];
    float decay = 1.0f / (1.0f + __expf(-dlv));   // sigmoid
    l2d = __log2f(decay);
  } else if (MODE == 2) {
    mul = scal[0];
  }

#pragma unroll
  for (int s = 0; s < NSUB; ++s) {
#pragma unroll
    for (int m = 0; m < MF; ++m) {
#pragma unroll
      for (int n = 0; n < NF; ++n) {
#pragma unroll
        for (int j = 0; j < 4; ++j) {
          int row = bm + wr + m * 16 + cr + j;
          int col = bn + s * sstride + wc + n * 16 + cc;
          float val = acc[s][m][n][j];
          if (MODE == 1) {
            int diff = col - row;
            float w = (diff > 0 && col < 2048)
                          ? exp2f((float)(diff - 1) * l2d) : 0.0f;
            int lc = bx * 128 + (wc + n * 16 + cc);   // band-local column
            ((bf16u*)Cout)[(long)z * sC + (long)row * ldC + lc] = f2bf(val * w);
          } else if (MODE == 2) {
            ((float*)Cout)[(long)z * sC + (long)row * ldC + col] = val * mul;
          } else {
            ((bf16u*)Cout)[(long)z * sC + (long)row * ldC + col] = f2bf(val);
          }
        }
      }
    }
  }
}

// prep: one dispatch.  Blocks [0,8192): x f32->bf16 (float4/ushort4).
// Blocks [8192,10240): 32x32 transpose-convert tiles of the 4 weights.
__global__ __launch_bounds__(256)
void prep(const float4* __restrict__ x, ushort4* __restrict__ x16o,
          const float* __restrict__ Wq, const float* __restrict__ Wk,
          const float* __restrict__ Wv, const float* __restrict__ Wo,
          bf16u* __restrict__ WqT, bf16u* __restrict__ WkT,
          bf16u* __restrict__ WvT, bf16u* __restrict__ WoT)
{
  __shared__ float t[32][33];
  const int bid = blockIdx.x;
  const int tid = threadIdx.x;
  if (bid < 8192) {
    int i = bid * 256 + tid;
    float4 v = x[i];
    ushort4 o;
    o.x = f2bf(v.x); o.y = f2bf(v.y); o.z = f2bf(v.z); o.w = f2bf(v.w);
    x16o[i] = o;
    return;
  }
  const int wi = bid - 8192;
  const int w  = wi >> 9;          // weight id, 512 tiles each
  const int ti = wi & 511;
  const float* in; bf16u* out; int R, C;
  if (w == 0)      { in = Wq; out = WqT; R = 1024; C = 512; }
  else if (w == 1) { in = Wk; out = WkT; R = 1024; C = 512; }
  else if (w == 2) { in = Wv; out = WvT; R = 1024; C = 512; }
  else             { in = Wo; out = WoT; R = 512;  C = 1024; }
  const int nx = C >> 5;
  const int c0 = (ti % nx) * 32, r0 = (ti / nx) * 32;
  const int tx = tid & 31, ty = tid >> 5;   // 32 x 8
#pragma unroll
  for (int i = 0; i < 4; ++i)
    t[ty + 8 * i][tx] = in[(long)(r0 + ty + 8 * i) * C + c0 + tx];
  __syncthreads();
#pragma unroll
  for (int i = 0; i < 4; ++i)
    out[(long)(c0 + ty + 8 * i) * R + r0 + tx] = f2bf(t[tx][ty + 8 * i]);
}

// batched strided bf16 transpose: in [R x C, row-stride ldIn] -> out [C][R]
__global__ void tr16(const bf16u* __restrict__ in, bf16u* __restrict__ out,
                     int R, int C, int ldIn, long sIn, long sOut) {
  __shared__ bf16u t[32][33];
  in  += (long)blockIdx.z * sIn;
  out += (long)blockIdx.z * sOut;
  int c0 = blockIdx.x * 32, r0 = blockIdx.y * 32;
  int tx = threadIdx.x, ty = threadIdx.y;
#pragma unroll
  for (int i = 0; i < 4; ++i)
    t[ty + 8 * i][tx] = in[(long)(r0 + ty + 8 * i) * ldIn + c0 + tx];
  __syncthreads();
#pragma unroll
  for (int i = 0; i < 4; ++i)
    out[(long)(c0 + ty + 8 * i) * R + r0 + tx] = t[tx][ty + 8 * i];
}

extern "C" void kernel_launch(void* const* d_in, const int* in_sizes, int n_in,
                              void* d_out, int out_size, void* d_ws, size_t ws_size,
                              hipStream_t stream) {
  const float* x  = (const float*)d_in[0];
  const float* dl = (const float*)d_in[1];
  const float* sc = (const float*)d_in[2];
  const float* Wq = (const float*)d_in[3];
  const float* Wk = (const float*)d_in[4];
  const float* Wv = (const float*)d_in[5];
  const float* Wo = (const float*)d_in[6];

  const int B = 4, T = 2048, V = 1024, D = 512;
  const long MT = (long)B * T;   // 8192
  const int QKV = 3 * D;         // 1536
  const int BAND = 256;          // 2 x 128 band columns (delta 0..1)

  char* p = (char*)d_ws;
  auto alloc = [&](size_t bytes) { char* r = p; p += bytes; return r; };
  bf16u* x16 = (bf16u*)alloc((size_t)MT * V * 2);        // 16 MB
  bf16u* WqT = (bf16u*)alloc((size_t)D * V * 2);         // contiguous [1536][V]
  bf16u* WkT = (bf16u*)alloc((size_t)D * V * 2);
  bf16u* WvT = (bf16u*)alloc((size_t)D * V * 2);
  bf16u* WoT = (bf16u*)alloc((size_t)V * D * 2);
  bf16u* qkv = (bf16u*)alloc((size_t)MT * QKV * 2);      // 25 MB
  bf16u* vT  = (bf16u*)alloc((size_t)MT * D * 2 + 4096); // 8 MB + guard
  bf16u* Sb  = (bf16u*)alloc((size_t)B * T * BAND * 2);  // 4.2 MB band
  bf16u* R   = (bf16u*)alloc((size_t)MT * D * 2);        // 8 MB

  // 1. prep: x -> bf16 + all 4 weight transposes, one dispatch
  prep<<<dim3(8192 + 2048), 256, 0, stream>>>(
      (const float4*)x, (ushort4*)x16, Wq, Wk, Wv, Wo, WqT, WkT, WvT, WoT);

  // 2. qkv = x16 @ [Wq|Wk|Wv]^T  (M=8192, N=1536, K=1024)
  //    NSUB=3: block tile 128 x 384, grid 64 x 4 = 256 = 1 block/CU.
  gemm_bt<0, 3><<<dim3(64 * 4, 1, 1), 256, 0, stream>>>(
      x16, WqT, qkv, V, V, V, QKV, 0, 0, 0, 4, nullptr);

  // 3. v transpose per batch: [T][D] (stride 1536) -> [D][T]
  tr16<<<dim3(D / 32, T / 32, B), dim3(32, 8), 0, stream>>>(
      qkv + 2 * D, vT, T, D, QKV, (long)T * QKV, (long)D * T);

  // 4. banded scores: S_band[b][t][delta*128+c], 128^2 tiles
  gemm_bt<1, 1><<<dim3(16 * 2, 1, B), 256, 0, stream>>>(
      qkv, qkv + D, Sb, D, QKV, QKV, BAND,
      (long)T * QKV, (long)T * QKV, (long)T * BAND, 2, dl);

  // 5. banded retrieved: R rows [bm,+128) = S_band @ v[s = bm..bm+256)
  gemm_bt<3, 1><<<dim3(16 * 4, 1, B), 256, 0, stream>>>(
      Sb, vT, R, BAND, BAND, T, D,
      (long)T * BAND, (long)1 << 20, (long)T * D, 4, nullptr);

  // 6. out = R @ Wo^T * scale  (M=8192, N=1024, K=512)
  //    NSUB=2: block tile 128 x 256, grid 64 x 4 = 256 = 1 block/CU.
  gemm_bt<2, 2><<<dim3(64 * 4, 1, 1), 256, 0, stream>>>(
      R, WoT, d_out, D, D, D, V, 0, 0, 0, 4, sc);
}